// Round 5
// baseline (138.116 us; speedup 1.0000x reference)
//
#include <hip/hip_runtime.h>

// TopologyAwareAttention — ONE kernel, load-polling grid barrier (no memset).
//  f(t) = sum_e relu(t*w1[e]+b1[e]) * mean_h(w2[e,h]) + mean(b2)   (head-mean first)
//  centers on 16x16 grid => d2 = dx^2+dy^2 in [0,450] => 451-entry LUT per batch
//  mean distance via cell histogram: sum = SUM_{c1,c2} h[c1] h[c2] sqrt(d2)
// Cost model (R1-R4): dur = ~42us harness ws-fill (fixed) + ~10us/node + kernels.
// R2 lesson: RMW-polling barrier = ~40us/crossing. This barrier: per-block slot
// release-STORE + acquire-LOAD polling (loads don't serialize), MAGIC value so
// the 0xAA-poisoned ws needs no zeroing. R3 lesson: redundant per-block stats ok
// only if cheap — sqrt table + LDS staging, 450 blocks not 1584.

#define NQ    900
#define LUT_N 451
#define NBLK  450
#define MAGIC 0x13572468

__device__ __forceinline__ int aload_acq(int* p) {
    return __hip_atomic_load(p, __ATOMIC_ACQUIRE, __HIP_MEMORY_SCOPE_AGENT);
}
__device__ __forceinline__ int aload_rlx(int* p) {
    return __hip_atomic_load(p, __ATOMIC_RELAXED, __HIP_MEMORY_SCOPE_AGENT);
}
__device__ __forceinline__ void astore_rel(int* p, int v) {
    __hip_atomic_store(p, v, __ATOMIC_RELEASE, __HIP_MEMORY_SCOPE_AGENT);
}
__device__ __forceinline__ void astore_rlx(int* p, int v) {
    __hip_atomic_store(p, v, __ATOMIC_RELAXED, __HIP_MEMORY_SCOPE_AGENT);
}

__global__ __launch_bounds__(256, 2)
void fused(const float* __restrict__ attn,
           const float* __restrict__ ref,
           const float* __restrict__ lam_p,
           const float* __restrict__ w1,
           const float* __restrict__ b1,
           const float* __restrict__ w2,
           const float* __restrict__ b2,
           float* __restrict__ out,
           int* __restrict__ ws) {
    int* cent_w = ws;            // [450] packed 4 x u8 centers
    int* slots  = ws + NBLK;     // [450] arrival flags (poison != MAGIC)

    __shared__ int   idx_s[NQ];
    __shared__ float sqs[LUT_N];     // sqrt(s)
    __shared__ float lut_s[LUT_N];
    __shared__ int   hsh[256];
    __shared__ float w1s[256], b1s[256], wbars[256];
    __shared__ float wsum[4];
    __shared__ int   ctmp[4];

    const int tid  = threadIdx.x;
    const int lane = tid & 63;
    const int wave = tid >> 6;
    const int blk  = blockIdx.x;

    // ---- P1: one wave per query argmax (queries blk*4 .. blk*4+3) ----
    {
        int q = blk * 4 + wave;
        const float* p = ref + (size_t)q * 256;
        float bv = p[lane];
        int   bi = lane;
        #pragma unroll
        for (int k = 1; k < 4; ++k) {
            float v = p[lane + 64 * k];
            if (v > bv) { bv = v; bi = lane + 64 * k; }   // strict > keeps first max
        }
        #pragma unroll
        for (int off = 32; off >= 1; off >>= 1) {
            float ov = __shfl_down(bv, off, 64);
            int   oi = __shfl_down(bi, off, 64);
            if (ov > bv || (ov == bv && oi < bi)) { bv = ov; bi = oi; }
        }
        if (lane == 0) ctmp[wave] = bi;     // bi = iy*16 + ix, fits u8
    }
    // overlap: stage constants while argmax waves finish
    hsh[tid] = 0;
    w1s[tid] = w1[tid];
    b1s[tid] = b1[tid];
    {
        float s8 = 0.f;
        #pragma unroll
        for (int h = 0; h < 8; ++h) s8 += w2[tid * 8 + h];
        wbars[tid] = s8 * 0.125f;
    }
    for (int s = tid; s < LUT_N; s += 256) sqs[s] = sqrtf((float)s);
    __syncthreads();

    if (tid == 0) {
        int wv = (ctmp[0] & 255) | ((ctmp[1] & 255) << 8) |
                 ((ctmp[2] & 255) << 16) | ((ctmp[3] & 255) << 24);
        astore_rlx(&cent_w[blk], wv);
        astore_rel(&slots[blk], MAGIC);     // release: orders cent_w before flag
    }

    // ---- grid barrier: every thread acquire-polls <=2 slots ----
    for (int s = tid; s < NBLK; s += 256)
        while (aload_acq(&slots[s]) != MAGIC) __builtin_amdgcn_s_sleep(8);
    __syncthreads();

    // ---- P2: per-block stats + LUT (cheap, redundant across 450 blocks) ----
    const int r0 = blk * 4;                 // linear row 0..1796
    const int b3 = (r0 >= NQ) ? 1 : 0;
    const int i0 = r0 - b3 * NQ;

    if (tid < 225) {                        // unpack my batch's 900 centers
        int wv = aload_rlx(&cent_w[b3 * 225 + tid]);
        int base = tid * 4;
        idx_s[base + 0] =  wv        & 255;
        idx_s[base + 1] = (wv >> 8)  & 255;
        idx_s[base + 2] = (wv >> 16) & 255;
        idx_s[base + 3] = (wv >> 24) & 255;
    }
    __syncthreads();

    for (int k = tid; k < NQ; k += 256) atomicAdd(&hsh[idx_s[k]], 1);
    __syncthreads();

    float local = 0.f;
    {
        int h2v = hsh[tid];                 // thread owns c2 = tid
        if (h2v) {
            int ix2 = tid & 15, iy2 = tid >> 4;
            for (int c1 = 0; c1 < 256; ++c1) {
                int h1 = hsh[c1];           // broadcast read, conflict-free
                int dx = (c1 & 15) - ix2;
                int dy = (c1 >> 4) - iy2;
                local += (float)h1 * sqs[dx * dx + dy * dy];
            }
            local *= (float)h2v;
        }
    }
    #pragma unroll
    for (int off = 32; off >= 1; off >>= 1) local += __shfl_down(local, off, 64);
    if (lane == 0) wsum[wave] = local;
    __syncthreads();

    float tot   = wsum[0] + wsum[1] + wsum[2] + wsum[3];
    float mean  = tot * (1.f / 15.f) * (1.f / ((float)NQ * (float)NQ));
    float inv   = 1.f / (mean + 1e-6f);
    float b2bar = 0.125f * (b2[0] + b2[1] + b2[2] + b2[3] +
                            b2[4] + b2[5] + b2[6] + b2[7]);
    float lam   = lam_p[0];

    for (int s = tid; s < LUT_N; s += 256) {
        float t   = sqs[s] * (1.f / 15.f) * inv;
        float acc = b2bar;
        for (int i = 0; i < 256; ++i) {     // all-LDS, broadcast reads
            float hv = fmaf(t, w1s[i], b1s[i]);
            acc = fmaf(fmaxf(hv, 0.f), wbars[i], acc);
        }
        lut_s[s] = lam * acc;
    }
    __syncthreads();

    // ---- P3: apply rows r0..r0+3 (all same batch since 900 % 4 == 0) ----
    for (int e = tid; e < 900; e += 256) {  // 4 rows x 225 float4
        int lr  = e / 225;
        int c4  = (e - lr * 225) * 4;
        int i   = i0 + lr;
        int ci  = idx_s[i];
        int ixi = ci & 15, iyi = ci >> 4;
        size_t base = (size_t)(b3 * NQ + i) * NQ + c4;
        float4 a = *(const float4*)(attn + base);
        float r[4] = {a.x, a.y, a.z, a.w};
        #pragma unroll
        for (int u = 0; u < 4; ++u) {
            int cj = idx_s[c4 + u];
            int dx = ixi - (cj & 15), dy = iyi - (cj >> 4);
            r[u] += lut_s[dx * dx + dy * dy];
        }
        *(float4*)(out + base) = make_float4(r[0], r[1], r[2], r[3]);
    }
}

extern "C" void kernel_launch(void* const* d_in, const int* in_sizes, int n_in,
                              void* d_out, int out_size, void* d_ws, size_t ws_size,
                              hipStream_t stream) {
    const float* attn = (const float*)d_in[0];   // [2,900,900]
    const float* ref  = (const float*)d_in[1];   // [2,900,16,16]
    const float* lam  = (const float*)d_in[2];
    const float* w1   = (const float*)d_in[3];   // [256]
    const float* b1   = (const float*)d_in[4];   // [256]
    const float* w2   = (const float*)d_in[5];   // [256,8]
    const float* b2   = (const float*)d_in[6];   // [8]
    float* out = (float*)d_out;
    int*   ws  = (int*)d_ws;                     // cent_w[450] + slots[450]

    fused<<<NBLK, 256, 0, stream>>>(attn, ref, lam, w1, b1, w2, b2, out, ws);
}

// Round 6
// 97.746 us; speedup vs baseline: 1.4130x; 1.4130x over previous
//
#include <hip/hip_runtime.h>

// TopologyAwareAttention — ONE kernel, fence-free sync via self-validating words.
//  f(t) = sum_e relu(t*w1[e]+b1[e]) * mean_h(w2[e,h]) + mean(b2)   (head-mean first)
//  centers on 16x16 grid => d2 = dx^2+dy^2 in [0,450] => 451-entry LUT per batch
//  mean distance via cell histogram: sum = SUM_{c1,c2} h[c1] h[c2] sqrt(d2)
// Sync lessons: R2 RMW-poll ~40us (RMW serialization); R5 acquire-poll ~60us
// (per-poll cache invalidates). Here: polls are RELAXED agent loads only.
// Centers words carry a 0xC0DE tag (poison 0xAAAAAAAA can't match) => validity
// rides with data, no fences. LUT: 2 producer blocks -> release fence -> flag;
// consumers poll flag relaxed, ONE acquire fence after success.
// Cost model: dur ~= 56us harness fills + ~10us/node + kernel time.

#define NQ    900
#define LUT_N 451
#define NBLK  450
#define TAG   0xC0DE0000u
#define MAGIC 0x13572468

__device__ __forceinline__ int aload_rlx(const int* p) {
    return __hip_atomic_load(p, __ATOMIC_RELAXED, __HIP_MEMORY_SCOPE_AGENT);
}
__device__ __forceinline__ void astore_rlx(int* p, int v) {
    __hip_atomic_store(p, v, __ATOMIC_RELAXED, __HIP_MEMORY_SCOPE_AGENT);
}

__global__ __launch_bounds__(256, 2)
void fused(const float* __restrict__ attn,
           const float* __restrict__ ref,
           const float* __restrict__ lam_p,
           const float* __restrict__ w1,
           const float* __restrict__ b1,
           const float* __restrict__ w2,
           const float* __restrict__ b2,
           float* __restrict__ out,
           int* __restrict__ ws) {
    int* cent2 = ws;            // [900] word k = TAG | c(2k)<<8 | c(2k+1)
    int* flag2 = ws + 900;      // [2]
    int* lutg  = ws + 904;      // [2][451] float bits

    __shared__ int   idx_s[NQ];
    __shared__ float lut_s[LUT_N];
    __shared__ float sqs[LUT_N];
    __shared__ int   hsh[256];
    __shared__ float w1s[256], b1s[256], wbars[256];
    __shared__ float wsum[4];
    __shared__ int   ctmp[4];

    const int tid  = threadIdx.x;
    const int lane = tid & 63;
    const int wave = tid >> 6;
    const int blk  = blockIdx.x;

    const int r0 = blk * 4;                  // linear row 0..1796
    const int b3 = (r0 >= NQ) ? 1 : 0;       // apply batch
    const int i0 = r0 - b3 * NQ;
    const bool producer = (blk == 0 || blk == 225);  // producer batch == b3

    // ---- P1: one wave per query argmax (queries blk*4 .. blk*4+3) ----
    {
        int q = blk * 4 + wave;
        const float* p = ref + (size_t)q * 256;
        float bv = p[lane];
        int   bi = lane;
        #pragma unroll
        for (int k = 1; k < 4; ++k) {
            float v = p[lane + 64 * k];
            if (v > bv) { bv = v; bi = lane + 64 * k; }   // strict > keeps first max
        }
        #pragma unroll
        for (int off = 32; off >= 1; off >>= 1) {
            float ov = __shfl_down(bv, off, 64);
            int   oi = __shfl_down(bi, off, 64);
            if (ov > bv || (ov == bv && oi < bi)) { bv = ov; bi = oi; }
        }
        if (lane == 0) ctmp[wave] = bi;      // bi = iy*16 + ix, fits u8
    }
    if (producer) {                           // stage producer-only tables
        hsh[tid] = 0;
        w1s[tid] = w1[tid];
        b1s[tid] = b1[tid];
        float s8 = 0.f;
        #pragma unroll
        for (int h = 0; h < 8; ++h) s8 += w2[tid * 8 + h];
        wbars[tid] = s8 * 0.125f;
        for (int s = tid; s < LUT_N; s += 256) sqs[s] = sqrtf((float)s);
    }
    __syncthreads();

    if (tid == 0) {                           // publish self-validating words
        int w0 = (int)(TAG | ((ctmp[0] & 255) << 8) | (ctmp[1] & 255));
        int w1v = (int)(TAG | ((ctmp[2] & 255) << 8) | (ctmp[3] & 255));
        astore_rlx(&cent2[blk * 2 + 0], w0);
        astore_rlx(&cent2[blk * 2 + 1], w1v);
    }

    if (producer) {
        // ---- gather all 450 words of my batch (relaxed poll, no fences) ----
        for (int k = tid; k < 450; k += 256) {
            int w;
            while (((unsigned)(w = aload_rlx(&cent2[450 * b3 + k])) & 0xFFFF0000u) != TAG)
                __builtin_amdgcn_s_sleep(2);
            idx_s[2 * k]     = (w >> 8) & 255;
            idx_s[2 * k + 1] =  w       & 255;
        }
        __syncthreads();

        // ---- histogram + pairwise distance sum ----
        for (int k = tid; k < NQ; k += 256) atomicAdd(&hsh[idx_s[k]], 1);
        __syncthreads();
        float local = 0.f;
        {
            int h2v = hsh[tid];               // thread owns c2 = tid
            if (h2v) {
                int ix2 = tid & 15, iy2 = tid >> 4;
                for (int c1 = 0; c1 < 256; ++c1) {
                    int h1 = hsh[c1];         // broadcast read
                    int dx = (c1 & 15) - ix2;
                    int dy = (c1 >> 4) - iy2;
                    local += (float)h1 * sqs[dx * dx + dy * dy];
                }
                local *= (float)h2v;
            }
        }
        #pragma unroll
        for (int off = 32; off >= 1; off >>= 1) local += __shfl_down(local, off, 64);
        if (lane == 0) wsum[wave] = local;
        __syncthreads();

        float tot   = wsum[0] + wsum[1] + wsum[2] + wsum[3];
        float mean  = tot * (1.f / 15.f) * (1.f / ((float)NQ * (float)NQ));
        float inv   = 1.f / (mean + 1e-6f);
        float b2bar = 0.125f * (b2[0] + b2[1] + b2[2] + b2[3] +
                                b2[4] + b2[5] + b2[6] + b2[7]);
        float lam   = lam_p[0];

        for (int s = tid; s < LUT_N; s += 256) {
            float t   = sqs[s] * (1.f / 15.f) * inv;
            float acc = b2bar;
            for (int i = 0; i < 256; ++i) {
                float hv = fmaf(t, w1s[i], b1s[i]);
                acc = fmaf(fmaxf(hv, 0.f), wbars[i], acc);
            }
            float v = lam * acc;
            lut_s[s] = v;
            astore_rlx(&lutg[b3 * LUT_N + s], __float_as_int(v));
        }
        __syncthreads();
        if (tid == 0) {
            __builtin_amdgcn_fence(__ATOMIC_RELEASE, "agent");
            astore_rlx(&flag2[b3], MAGIC);
        }
        // idx_s, lut_s ready for apply
    } else {
        // ---- consumers: poll ONE flag word (relaxed), then one acquire ----
        if (tid == 0) {
            while (aload_rlx(&flag2[b3]) != MAGIC) __builtin_amdgcn_s_sleep(8);
        }
        __syncthreads();
        __builtin_amdgcn_fence(__ATOMIC_ACQUIRE, "agent");
        for (int k = tid; k < 450; k += 256) {
            int w = aload_rlx(&cent2[450 * b3 + k]);   // valid before flag2
            idx_s[2 * k]     = (w >> 8) & 255;
            idx_s[2 * k + 1] =  w       & 255;
        }
        for (int s = tid; s < LUT_N; s += 256)
            lut_s[s] = __int_as_float(aload_rlx(&lutg[b3 * LUT_N + s]));
        __syncthreads();
    }

    // ---- P3: apply rows r0..r0+3 (all same batch since 900 % 4 == 0) ----
    for (int e = tid; e < 900; e += 256) {   // 4 rows x 225 float4
        int lr  = e / 225;
        int c4  = (e - lr * 225) * 4;
        int i   = i0 + lr;
        int ci  = idx_s[i];
        int ixi = ci & 15, iyi = ci >> 4;
        size_t base = (size_t)(b3 * NQ + i) * NQ + c4;
        float4 a = *(const float4*)(attn + base);
        float r[4] = {a.x, a.y, a.z, a.w};
        #pragma unroll
        for (int u = 0; u < 4; ++u) {
            int cj = idx_s[c4 + u];
            int dx = ixi - (cj & 15), dy = iyi - (cj >> 4);
            r[u] += lut_s[dx * dx + dy * dy];
        }
        *(float4*)(out + base) = make_float4(r[0], r[1], r[2], r[3]);
    }
}

extern "C" void kernel_launch(void* const* d_in, const int* in_sizes, int n_in,
                              void* d_out, int out_size, void* d_ws, size_t ws_size,
                              hipStream_t stream) {
    const float* attn = (const float*)d_in[0];   // [2,900,900]
    const float* ref  = (const float*)d_in[1];   // [2,900,16,16]
    const float* lam  = (const float*)d_in[2];
    const float* w1   = (const float*)d_in[3];   // [256]
    const float* b1   = (const float*)d_in[4];   // [256]
    const float* w2   = (const float*)d_in[5];   // [256,8]
    const float* b2   = (const float*)d_in[6];   // [8]
    float* out = (float*)d_out;
    int*   ws  = (int*)d_ws;                     // cent2[900] flag2[2] lutg[902]

    fused<<<NBLK, 256, 0, stream>>>(attn, ref, lam, w1, b1, w2, b2, out, ws);
}

// Round 7
// 87.129 us; speedup vs baseline: 1.5852x; 1.1219x over previous
//
#include <hip/hip_runtime.h>

// TopologyAwareAttention — 2 kernels; the ONLY in-kernel waiters are the two
// stats blocks (one per batch) polling distinct self-validating words.
//  f(t) = sum_e relu(t*w1[e]+b1[e]) * mean_h(w2[e,h]) + mean(b2)   (head-mean first)
//  centers on 16x16 grid => d2 = dx^2+dy^2 in [0,450] => 451-entry LUT per batch
//  mean distance via cell histogram: sum = SUM_{c1,c2} h[c1] h[c2] sqrt(d2)
// Sync lessons (R2/R5/R6): grid-wide in-kernel sync = 25-60us regardless of
// mechanism (RMW-poll / acquire-poll / relaxed+flag fan-out). Kernel boundary
// is the only cheap device-wide sync. Node removal saves ~8us/node (R1->R4).
// Tagged words: high16 = 0xC0DE, poison 0xAA bytes can never match; validity
// rides with the data => relaxed loads only, no fences in poll loops.

#define NQ    900
#define LUT_N 451
#define TAG   0xC0DE0000u

__device__ __forceinline__ int aload_rlx(const int* p) {
    return __hip_atomic_load(p, __ATOMIC_RELAXED, __HIP_MEMORY_SCOPE_AGENT);
}
__device__ __forceinline__ void astore_rlx(int* p, int v) {
    __hip_atomic_store(p, v, __ATOMIC_RELAXED, __HIP_MEMORY_SCOPE_AGENT);
}

// ws layout: cent2[900] tagged words (word k of batch b at cent2[b*450 + k-local]
// holds centers of local queries 2k,2k+1), then lutg[2][451] float bits.
__global__ __launch_bounds__(256)
void k1_centers_stats(const float* __restrict__ ref,
                      const float* __restrict__ lam_p,
                      const float* __restrict__ w1,
                      const float* __restrict__ b1,
                      const float* __restrict__ w2,
                      const float* __restrict__ b2,
                      int* __restrict__ ws) {
    int*   cent2 = ws;
    float* lutg  = (float*)(ws + 900);

    const int tid  = threadIdx.x;
    const int lane = tid & 63;
    const int wave = tid >> 6;
    const int blk  = blockIdx.x;

    if (blk < 450) {
        // ---- argmax: one wave per query, 4 queries per block ----
        __shared__ int ctmp[4];
        int q = blk * 4 + wave;                 // 0..1799
        const float* p = ref + (size_t)q * 256;
        float bv = p[lane];
        int   bi = lane;
        #pragma unroll
        for (int k = 1; k < 4; ++k) {
            float v = p[lane + 64 * k];
            if (v > bv) { bv = v; bi = lane + 64 * k; }   // strict > keeps first max
        }
        #pragma unroll
        for (int off = 32; off >= 1; off >>= 1) {
            float ov = __shfl_down(bv, off, 64);
            int   oi = __shfl_down(bi, off, 64);
            if (ov > bv || (ov == bv && oi < bi)) { bv = ov; bi = oi; }
        }
        if (lane == 0) ctmp[wave] = bi;         // iy*16+ix, fits u8
        __syncthreads();
        if (tid == 0) {
            // word index blk*2 == b*450 + local_word  (blocks 225.. are batch 1)
            int w0 = (int)(TAG | ((ctmp[0] & 255) << 8) | (ctmp[1] & 255));
            int w1v = (int)(TAG | ((ctmp[2] & 255) << 8) | (ctmp[3] & 255));
            astore_rlx(&cent2[blk * 2 + 0], w0);
            astore_rlx(&cent2[blk * 2 + 1], w1v);
        }
        return;
    }

    // ---- stats block for batch b: poll 450 distinct tagged words ----
    const int b = blk - 450;                    // 0 or 1
    __shared__ int   idx_s[NQ];
    __shared__ float sqs[LUT_N];
    __shared__ int   hsh[256];
    __shared__ float w1s[256], b1s[256], wbars[256];
    __shared__ float wsum[4];

    hsh[tid] = 0;
    w1s[tid] = w1[tid];
    b1s[tid] = b1[tid];
    {
        float s8 = 0.f;
        #pragma unroll
        for (int h = 0; h < 8; ++h) s8 += w2[tid * 8 + h];
        wbars[tid] = s8 * 0.125f;
    }
    for (int s = tid; s < LUT_N; s += 256) sqs[s] = sqrtf((float)s);

    for (int k = tid; k < 450; k += 256) {      // <=2 words per thread, all distinct
        int w;
        while (((unsigned)(w = aload_rlx(&cent2[b * 450 + k])) & 0xFFFF0000u) != TAG)
            __builtin_amdgcn_s_sleep(1);
        idx_s[2 * k]     = (w >> 8) & 255;
        idx_s[2 * k + 1] =  w       & 255;
    }
    __syncthreads();

    for (int k = tid; k < NQ; k += 256) atomicAdd(&hsh[idx_s[k]], 1);
    __syncthreads();

    float local = 0.f;
    {
        int h2v = hsh[tid];                     // thread owns c2 = tid
        if (h2v) {
            int ix2 = tid & 15, iy2 = tid >> 4;
            for (int c1 = 0; c1 < 256; ++c1) {
                int h1 = hsh[c1];               // broadcast read
                int dx = (c1 & 15) - ix2;
                int dy = (c1 >> 4) - iy2;
                local += (float)h1 * sqs[dx * dx + dy * dy];
            }
            local *= (float)h2v;
        }
    }
    #pragma unroll
    for (int off = 32; off >= 1; off >>= 1) local += __shfl_down(local, off, 64);
    if (lane == 0) wsum[wave] = local;
    __syncthreads();

    float tot   = wsum[0] + wsum[1] + wsum[2] + wsum[3];
    float mean  = tot * (1.f / 15.f) * (1.f / ((float)NQ * (float)NQ));
    float inv   = 1.f / (mean + 1e-6f);
    float b2bar = 0.125f * (b2[0] + b2[1] + b2[2] + b2[3] +
                            b2[4] + b2[5] + b2[6] + b2[7]);
    float lam   = lam_p[0];

    for (int s = tid; s < LUT_N; s += 256) {
        float t   = sqs[s] * (1.f / 15.f) * inv;
        float acc = b2bar;
        for (int i = 0; i < 256; ++i) {
            float hv = fmaf(t, w1s[i], b1s[i]);
            acc = fmaf(fmaxf(hv, 0.f), wbars[i], acc);
        }
        lutg[b * LUT_N + s] = lam * acc;        // plain store; kernel boundary flushes
    }
}

__global__ __launch_bounds__(256)
void k2_apply(const float* __restrict__ attn,
              const int* __restrict__ ws,
              float* __restrict__ out) {
    const int* cent2 = ws;
    const float* lutg = (const float*)(ws + 900);
    int b = blockIdx.y;
    __shared__ float lut_s[LUT_N];
    __shared__ int   idx_s[NQ];
    for (int k = threadIdx.x; k < 450; k += 256) {
        int w = cent2[b * 450 + k];             // valid: written before K1 ended
        idx_s[2 * k]     = (w >> 8) & 255;
        idx_s[2 * k + 1] =  w       & 255;
    }
    for (int k = threadIdx.x; k < LUT_N; k += 256) lut_s[k] = lutg[b * LUT_N + k];
    __syncthreads();
    int t4 = blockIdx.x * 256 + threadIdx.x;    // one float4 per thread
    if (t4 >= NQ * NQ / 4) return;              // 202500 per batch
    int i  = t4 / 225;                          // 225 float4 per row
    int j0 = (t4 - i * 225) * 4;
    int ci = idx_s[i];
    int ixi = ci & 15, iyi = ci >> 4;
    size_t base = (size_t)b * (NQ * NQ) + (size_t)i * NQ + j0;
    float4 a = *(const float4*)(attn + base);
    float r[4] = {a.x, a.y, a.z, a.w};
    #pragma unroll
    for (int u = 0; u < 4; ++u) {
        int cj = idx_s[j0 + u];
        int dx = ixi - (cj & 15), dy = iyi - (cj >> 4);
        r[u] += lut_s[dx * dx + dy * dy];
    }
    *(float4*)(out + base) = make_float4(r[0], r[1], r[2], r[3]);
}

extern "C" void kernel_launch(void* const* d_in, const int* in_sizes, int n_in,
                              void* d_out, int out_size, void* d_ws, size_t ws_size,
                              hipStream_t stream) {
    const float* attn = (const float*)d_in[0];   // [2,900,900]
    const float* ref  = (const float*)d_in[1];   // [2,900,16,16]
    const float* lam  = (const float*)d_in[2];
    const float* w1   = (const float*)d_in[3];   // [256]
    const float* b1   = (const float*)d_in[4];   // [256]
    const float* w2   = (const float*)d_in[5];   // [256,8]
    const float* b2   = (const float*)d_in[6];   // [8]
    float* out = (float*)d_out;
    int*   ws  = (int*)d_ws;                     // cent2[900] + lutg[902]

    k1_centers_stats<<<452, 256, 0, stream>>>(ref, lam, w1, b1, w2, b2, ws);
    k2_apply<<<dim3((NQ * NQ / 4 + 255) / 256, 2), 256, 0, stream>>>(attn, ws, out);
}